// Round 2
// baseline (58.878 us; speedup 1.0000x reference)
//
#include <hip/hip_runtime.h>
#include <hip/hip_bf16.h>
#include <hip/hip_cooperative_groups.h>

namespace cg = cooperative_groups;

#define D 64
#define BU 1024
#define BI 4096
#define L 50

typedef __attribute__((ext_vector_type(4))) float f32x4;
typedef __attribute__((ext_vector_type(8))) short bf16x8;

__device__ __forceinline__ ushort f2bf(float x) {
    union { float f; unsigned u; } v; v.f = x;
    unsigned r = v.u + 0x7fff + ((v.u >> 16) & 1);  // round-to-nearest-even
    return (ushort)(r >> 16);
}

// One cooperative kernel: phase 1 gathers/reduces into ws, grid.sync, phase 2 GEMM.
// Grid = 256 blocks x 256 threads (1 block/CU -> co-residency guaranteed).
__global__ __launch_bounds__(256) void k_fused(
    const int* __restrict__ user_ids, const int* __restrict__ item_ids,
    const int* __restrict__ fb_idx, const float* __restrict__ fb_val,
    const float* __restrict__ uw, const float* __restrict__ ub,
    const float* __restrict__ iw, const float* __restrict__ ib,
    const float* __restrict__ bias, const float* __restrict__ We,
    ushort* __restrict__ eff, ushort* __restrict__ iwg,
    float* __restrict__ ubg, float* __restrict__ ibg,
    float* __restrict__ out) {
    const int t = threadIdx.x;
    const int b = blockIdx.x;
    const int wave = t >> 6;
    const int lane = t & 63;

    // ---- Phase 1a: eff rows, one user per wave (4 users/block, 1024 total) ----
    {
        const int u = b * 4 + wave;
        const int uid = user_ids[u];
        float acc = uw[uid * D + lane];
        const int*   __restrict__ ip = fb_idx + u * L;
        const float* __restrict__ vp = fb_val + u * L;
        #pragma unroll 10
        for (int l = 0; l < L; ++l)
            acc = fmaf(vp[l], We[ip[l] * D + lane], acc);
        eff[u * D + lane] = f2bf(acc);
        if (lane == 0) ubg[u] = ub[uid];
    }

    // ---- Phase 1b: gather+convert 16 item rows per block (4096 total) ----
    {
        const int it = b * 16 + (t >> 4);
        const int iid = item_ids[it];
        const int d4 = (t & 15) * 4;
        const float4 v = *(const float4*)(iw + (size_t)iid * D + d4);
        ushort4 o;
        o.x = f2bf(v.x); o.y = f2bf(v.y); o.z = f2bf(v.z); o.w = f2bf(v.w);
        *(ushort4*)(iwg + it * D + d4) = o;
        if (t < 16) ibg[b * 16 + t] = ib[item_ids[b * 16 + t]];
    }

    cg::this_grid().sync();

    // ---- Phase 2: GEMM. Block tile 64M x 256N; wave tile 64M x 64N. ----
    const int m0 = (b >> 4) * 64;                   // 16 m-blocks of 64 users
    const int n0 = (b & 15) * 256 + wave * 64;      // 16 n-blocks, wave picks 64 cols
    const int lr = lane & 15;
    const int g  = lane >> 4;

    bf16x8 a0[4], a1[4], b0[4], b1[4];
    #pragma unroll
    for (int mt = 0; mt < 4; ++mt) {
        const int row = m0 + mt * 16 + lr;
        a0[mt] = *(const bf16x8*)(eff + row * D + g * 8);
        a1[mt] = *(const bf16x8*)(eff + row * D + 32 + g * 8);
    }
    #pragma unroll
    for (int ct = 0; ct < 4; ++ct) {
        const int col = n0 + ct * 16 + lr;
        b0[ct] = *(const bf16x8*)(iwg + col * D + g * 8);
        b1[ct] = *(const bf16x8*)(iwg + col * D + 32 + g * 8);
    }

    f32x4 acc[4][4];
    #pragma unroll
    for (int mt = 0; mt < 4; ++mt)
        #pragma unroll
        for (int ct = 0; ct < 4; ++ct) {
            acc[mt][ct] = (f32x4){0.f, 0.f, 0.f, 0.f};
            acc[mt][ct] = __builtin_amdgcn_mfma_f32_16x16x32_bf16(a0[mt], b0[ct], acc[mt][ct], 0, 0, 0);
            acc[mt][ct] = __builtin_amdgcn_mfma_f32_16x16x32_bf16(a1[mt], b1[ct], acc[mt][ct], 0, 0, 0);
        }

    const float bb = bias[0];
    float ibc[4];
    #pragma unroll
    for (int ct = 0; ct < 4; ++ct) ibc[ct] = ibg[n0 + ct * 16 + lr] + bb;

    #pragma unroll
    for (int mt = 0; mt < 4; ++mt) {
        float ubr[4];
        #pragma unroll
        for (int r = 0; r < 4; ++r) ubr[r] = ubg[m0 + mt * 16 + g * 4 + r];
        #pragma unroll
        for (int ct = 0; ct < 4; ++ct) {
            const int col = n0 + ct * 16 + lr;
            #pragma unroll
            for (int r = 0; r < 4; ++r)
                out[(size_t)(m0 + mt * 16 + g * 4 + r) * BI + col] = acc[mt][ct][r] + ubr[r] + ibc[ct];
        }
    }
}

extern "C" void kernel_launch(void* const* d_in, const int* in_sizes, int n_in,
                              void* d_out, int out_size, void* d_ws, size_t ws_size,
                              hipStream_t stream) {
    const int*   user_ids = (const int*)  d_in[0];
    const int*   item_ids = (const int*)  d_in[1];
    const int*   fb_idx   = (const int*)  d_in[2];
    const float* fb_val   = (const float*)d_in[3];
    const float* uw       = (const float*)d_in[4];
    const float* ub       = (const float*)d_in[5];
    const float* iw       = (const float*)d_in[6];
    const float* ib       = (const float*)d_in[7];
    const float* bias     = (const float*)d_in[8];
    const float* We       = (const float*)d_in[9];

    char* ws = (char*)d_ws;
    ushort* eff = (ushort*)(ws);                         // 1024*64*2   = 131072 B
    ushort* iwg = (ushort*)(ws + 131072);                // 4096*64*2   = 524288 B
    float*  ubg = (float*)(ws + 131072 + 524288);        // 1024*4      = 4096 B
    float*  ibg = (float*)(ws + 131072 + 524288 + 4096); // 4096*4      = 16384 B
    float*  out = (float*)d_out;

    void* args[] = { (void*)&user_ids, (void*)&item_ids, (void*)&fb_idx, (void*)&fb_val,
                     (void*)&uw, (void*)&ub, (void*)&iw, (void*)&ib, (void*)&bias, (void*)&We,
                     (void*)&eff, (void*)&iwg, (void*)&ubg, (void*)&ibg, (void*)&out };
    hipLaunchCooperativeKernel((const void*)k_fused, dim3(256), dim3(256), args, 0, stream);
}

// Round 3
// 28.278 us; speedup vs baseline: 2.0821x; 2.0821x over previous
//
#include <hip/hip_runtime.h>
#include <hip/hip_bf16.h>

#define D 64
#define BU 1024
#define BI 4096
#define L 50

typedef __attribute__((ext_vector_type(4))) float f32x4;
typedef __attribute__((ext_vector_type(8))) short bf16x8;

__device__ __forceinline__ ushort f2bf(float x) {
    union { float f; unsigned u; } v; v.f = x;
    unsigned r = v.u + 0x7fff + ((v.u >> 16) & 1);  // round-to-nearest-even
    return (ushort)(r >> 16);
}

// Single dispatch, no workspace, no grid sync. Block = 16 users x 1024 items.
// Cross-block eff dependency removed by recomputing eff per block (4x dup).
__global__ __launch_bounds__(256) void k_all(
    const int* __restrict__ user_ids, const int* __restrict__ item_ids,
    const int* __restrict__ fb_idx, const float* __restrict__ fb_val,
    const float* __restrict__ uw, const float* __restrict__ ub,
    const float* __restrict__ iw, const float* __restrict__ ib,
    const float* __restrict__ bias, const float* __restrict__ We,
    float* __restrict__ out) {

    __shared__ int    s_idx[16 * L];
    __shared__ float  s_val[16 * L];
    __shared__ ushort s_eff[16 * D];
    __shared__ float  s_ub[16];

    const int t = threadIdx.x;
    const int b = blockIdx.x;
    const int bm = b >> 2;            // 64 m-tiles of 16 users
    const int bn = b & 3;             // 4 n-tiles of 1024 items
    const int m0 = bm * 16;
    const int wave = t >> 6;
    const int lane = t & 63;

    // Preload the 16 users' feedback rows (idx,val) into LDS.
    #pragma unroll
    for (int i = t; i < 16 * L; i += 256) {
        s_idx[i] = fb_idx[m0 * L + i];
        s_val[i] = fb_val[m0 * L + i];
    }
    __syncthreads();

    // ---- Phase 1: eff rows for 16 users, 4 per wave, lane = dim ----
    {
        float acc[4];
        int uid[4];
        #pragma unroll
        for (int s = 0; s < 4; ++s) {
            uid[s] = user_ids[m0 + wave * 4 + s];
            acc[s] = uw[(size_t)uid[s] * D + lane];
        }
        #pragma unroll 5
        for (int l = 0; l < L; ++l) {
            #pragma unroll
            for (int s = 0; s < 4; ++s) {
                const int ui = wave * 4 + s;
                const int ix = s_idx[ui * L + l];
                const float v = s_val[ui * L + l];
                acc[s] = fmaf(v, We[(size_t)ix * D + lane], acc[s]);
            }
        }
        #pragma unroll
        for (int s = 0; s < 4; ++s)
            s_eff[(wave * 4 + s) * D + lane] = f2bf(acc[s]);
        if (lane == 0) {
            #pragma unroll
            for (int s = 0; s < 4; ++s) s_ub[wave * 4 + s] = ub[uid[s]];
        }
    }
    __syncthreads();

    // ---- Phase 2: wave tile 16(M) x 256(N); B gathered fp32 -> bf16 in-reg ----
    const int lr = lane & 15;
    const int g  = lane >> 4;
    const int n0 = bn * 1024 + wave * 256;

    const bf16x8 a0 = *(const bf16x8*)(&s_eff[lr * D + g * 8]);
    const bf16x8 a1 = *(const bf16x8*)(&s_eff[lr * D + 32 + g * 8]);

    const float bb = bias[0];
    float ubr[4];
    #pragma unroll
    for (int r = 0; r < 4; ++r) ubr[r] = s_ub[g * 4 + r];

    #pragma unroll 4
    for (int ct = 0; ct < 16; ++ct) {
        const int col = n0 + ct * 16 + lr;
        const int iid = item_ids[col];
        const float* __restrict__ rp = iw + (size_t)iid * D + g * 8;
        const float4 f0 = *(const float4*)(rp);
        const float4 f1 = *(const float4*)(rp + 4);
        const float4 f2 = *(const float4*)(rp + 32);
        const float4 f3 = *(const float4*)(rp + 36);
        bf16x8 b0, b1;
        b0[0] = (short)f2bf(f0.x); b0[1] = (short)f2bf(f0.y);
        b0[2] = (short)f2bf(f0.z); b0[3] = (short)f2bf(f0.w);
        b0[4] = (short)f2bf(f1.x); b0[5] = (short)f2bf(f1.y);
        b0[6] = (short)f2bf(f1.z); b0[7] = (short)f2bf(f1.w);
        b1[0] = (short)f2bf(f2.x); b1[1] = (short)f2bf(f2.y);
        b1[2] = (short)f2bf(f2.z); b1[3] = (short)f2bf(f2.w);
        b1[4] = (short)f2bf(f3.x); b1[5] = (short)f2bf(f3.y);
        b1[6] = (short)f2bf(f3.z); b1[7] = (short)f2bf(f3.w);

        f32x4 a = (f32x4){0.f, 0.f, 0.f, 0.f};
        a = __builtin_amdgcn_mfma_f32_16x16x32_bf16(a0, b0, a, 0, 0, 0);
        a = __builtin_amdgcn_mfma_f32_16x16x32_bf16(a1, b1, a, 0, 0, 0);

        const float ibc = ib[iid] + bb;
        #pragma unroll
        for (int r = 0; r < 4; ++r)
            out[(size_t)(m0 + g * 4 + r) * BI + col] = a[r] + ubr[r] + ibc;
    }
}

extern "C" void kernel_launch(void* const* d_in, const int* in_sizes, int n_in,
                              void* d_out, int out_size, void* d_ws, size_t ws_size,
                              hipStream_t stream) {
    const int*   user_ids = (const int*)  d_in[0];
    const int*   item_ids = (const int*)  d_in[1];
    const int*   fb_idx   = (const int*)  d_in[2];
    const float* fb_val   = (const float*)d_in[3];
    const float* uw       = (const float*)d_in[4];
    const float* ub       = (const float*)d_in[5];
    const float* iw       = (const float*)d_in[6];
    const float* ib       = (const float*)d_in[7];
    const float* bias     = (const float*)d_in[8];
    const float* We       = (const float*)d_in[9];
    float* out = (float*)d_out;

    k_all<<<256, 256, 0, stream>>>(user_ids, item_ids, fb_idx, fb_val,
                                   uw, ub, iw, ib, bias, We, out);
}

// Round 4
// 20.542 us; speedup vs baseline: 2.8663x; 1.3766x over previous
//
#include <hip/hip_runtime.h>
#include <hip/hip_bf16.h>

#define D 64
#define BU 1024
#define BI 4096
#define L 50

typedef __attribute__((ext_vector_type(4))) float f32x4;
typedef __attribute__((ext_vector_type(8))) short bf16x8;

__device__ __forceinline__ ushort f2bf(float x) {
    union { float f; unsigned u; } v; v.f = x;
    unsigned r = v.u + 0x7fff + ((v.u >> 16) & 1);  // round-to-nearest-even
    return (ushort)(r >> 16);
}

// Prep: blocks [0,1024) = one user each (L split over 4 waves, LDS reduce).
//       blocks [1024,1152) = 32 item rows each, fp32->bf16 + bias gather.
__global__ __launch_bounds__(256) void k_prep(
    const int* __restrict__ user_ids, const int* __restrict__ item_ids,
    const int* __restrict__ fb_idx, const float* __restrict__ fb_val,
    const float* __restrict__ uw, const float* __restrict__ ub,
    const float* __restrict__ iw, const float* __restrict__ ib,
    const float* __restrict__ We,
    ushort* __restrict__ eff, ushort* __restrict__ iwg,
    float* __restrict__ ubg, float* __restrict__ ibg) {
    const int b = blockIdx.x;
    const int t = threadIdx.x;

    if (b < BU) {
        // ---- one user per block; 4 waves split L = 13+13+13+11 ----
        __shared__ float s_part[4][D];
        const int wave = t >> 6;
        const int lane = t & 63;
        const int u = b;
        const int lo = wave * 13;
        float acc = 0.f;
        #pragma unroll
        for (int j = 0; j < 13; ++j) {
            const int l = lo + j;
            if (l < L) {
                const int   ix = fb_idx[u * L + l];
                const float v  = fb_val[u * L + l];
                acc = fmaf(v, We[(size_t)ix * D + lane], acc);
            }
        }
        s_part[wave][lane] = acc;
        __syncthreads();
        if (wave == 0) {
            const int uid = user_ids[u];
            const float r = uw[(size_t)uid * D + lane]
                          + s_part[0][lane] + s_part[1][lane]
                          + s_part[2][lane] + s_part[3][lane];
            eff[u * D + lane] = f2bf(r);
            if (lane == 0) ubg[u] = ub[uid];
        }
    } else {
        // ---- 32 item rows per block; 8 threads/row, 8 floats each ----
        const int base = (b - BU) * 32;
        const int row  = base + (t >> 3);
        const int seg  = (t & 7) * 8;
        const int iid  = item_ids[row];
        const float4 f0 = *(const float4*)(iw + (size_t)iid * D + seg);
        const float4 f1 = *(const float4*)(iw + (size_t)iid * D + seg + 4);
        bf16x8 o;
        o[0] = (short)f2bf(f0.x); o[1] = (short)f2bf(f0.y);
        o[2] = (short)f2bf(f0.z); o[3] = (short)f2bf(f0.w);
        o[4] = (short)f2bf(f1.x); o[5] = (short)f2bf(f1.y);
        o[6] = (short)f2bf(f1.z); o[7] = (short)f2bf(f1.w);
        *(bf16x8*)(iwg + row * D + seg) = o;
        if (t < 32) ibg[base + t] = ib[item_ids[base + t]];
    }
}

// GEMM: per-wave 16(M)x64(N) tile via 8x mfma_f32_16x16x32_bf16, K=64.
// (proven in round 1) grid (16 n, 64 m) x 256 thr = 1024 blocks, 4/CU.
__global__ __launch_bounds__(256) void k_gemm(
    const ushort* __restrict__ eff, const ushort* __restrict__ iwg,
    const float* __restrict__ ubg, const float* __restrict__ ibg,
    const float* __restrict__ bias, float* __restrict__ out) {
    const int lane = threadIdx.x & 63;
    const int wave = threadIdx.x >> 6;
    const int m0 = blockIdx.y * 16;
    const int n0 = blockIdx.x * 256 + wave * 64;
    const int lr = lane & 15;
    const int g  = lane >> 4;

    const bf16x8 a0 = *(const bf16x8*)(eff + (m0 + lr) * D + g * 8);
    const bf16x8 a1 = *(const bf16x8*)(eff + (m0 + lr) * D + 32 + g * 8);

    f32x4 acc[4];
    #pragma unroll
    for (int c = 0; c < 4; ++c) {
        acc[c] = (f32x4){0.f, 0.f, 0.f, 0.f};
        const int col = n0 + c * 16 + lr;
        const bf16x8 b0 = *(const bf16x8*)(iwg + col * D + g * 8);
        const bf16x8 b1 = *(const bf16x8*)(iwg + col * D + 32 + g * 8);
        acc[c] = __builtin_amdgcn_mfma_f32_16x16x32_bf16(a0, b0, acc[c], 0, 0, 0);
        acc[c] = __builtin_amdgcn_mfma_f32_16x16x32_bf16(a1, b1, acc[c], 0, 0, 0);
    }

    const float bb = bias[0];
    float ubr[4];
    #pragma unroll
    for (int r = 0; r < 4; ++r) ubr[r] = ubg[m0 + g * 4 + r];

    #pragma unroll
    for (int c = 0; c < 4; ++c) {
        const int col = n0 + c * 16 + lr;
        const float ibc = ibg[col] + bb;
        #pragma unroll
        for (int r = 0; r < 4; ++r)
            out[(size_t)(m0 + g * 4 + r) * BI + col] = acc[c][r] + ubr[r] + ibc;
    }
}

extern "C" void kernel_launch(void* const* d_in, const int* in_sizes, int n_in,
                              void* d_out, int out_size, void* d_ws, size_t ws_size,
                              hipStream_t stream) {
    const int*   user_ids = (const int*)  d_in[0];
    const int*   item_ids = (const int*)  d_in[1];
    const int*   fb_idx   = (const int*)  d_in[2];
    const float* fb_val   = (const float*)d_in[3];
    const float* uw       = (const float*)d_in[4];
    const float* ub       = (const float*)d_in[5];
    const float* iw       = (const float*)d_in[6];
    const float* ib       = (const float*)d_in[7];
    const float* bias     = (const float*)d_in[8];
    const float* We       = (const float*)d_in[9];

    char* ws = (char*)d_ws;
    ushort* eff = (ushort*)(ws);                         // 1024*64*2   = 131072 B
    ushort* iwg = (ushort*)(ws + 131072);                // 4096*64*2   = 524288 B
    float*  ubg = (float*)(ws + 131072 + 524288);        // 1024*4      = 4096 B
    float*  ibg = (float*)(ws + 131072 + 524288 + 4096); // 4096*4      = 16384 B
    float*  out = (float*)d_out;

    k_prep<<<BU + BI / 32, 256, 0, stream>>>(user_ids, item_ids, fb_idx, fb_val,
                                             uw, ub, iw, ib, We, eff, iwg, ubg, ibg);
    k_gemm<<<dim3(BI / 256, BU / 16), 256, 0, stream>>>(eff, iwg, ubg, ibg, bias, out);
}